// Round 11
// baseline (271.398 us; speedup 1.0000x reference)
//
#include <hip/hip_runtime.h>

typedef unsigned short u16;
typedef unsigned int   u32;
typedef __attribute__((ext_vector_type(8))) short bf16x8;
typedef __attribute__((ext_vector_type(4))) float f32x4;

#define SEQ 2048
#define DIM 1024
#define NH  16
#define DH  64
#define NROW 4096

static __device__ __forceinline__ float bf2f(u16 v){
  u32 u = ((u32)v) << 16; float f; __builtin_memcpy(&f, &u, 4); return f;
}
static __device__ __forceinline__ u16 f2bf(float f){
  u32 u; __builtin_memcpy(&u, &f, 4);
  u32 r = (u + 0x7fffu + ((u >> 16) & 1u)) >> 16;
  return (u16)r;
}
// round-half-up pack of two fp32 -> two bf16 in one u32 (low = a, high = b)
static __device__ __forceinline__ u32 pack2bf(float a, float b){
  u32 ua, ub; __builtin_memcpy(&ua, &a, 4); __builtin_memcpy(&ub, &b, 4);
  return ((ua + 0x8000u) >> 16) | ((ub + 0x8000u) & 0xFFFF0000u);
}

#define GLD_LDS(gp, lp) \
  __builtin_amdgcn_global_load_lds( \
      (const __attribute__((address_space(1))) void*)(gp), \
      (__attribute__((address_space(3))) void*)(lp), 16, 0, 0)

// ---------------- RMSNorm: x[4096][1024] fp32 -> h bf16 ----------------
__global__ __launch_bounds__(256) void k_rmsnorm(const float* __restrict__ x,
                                                 const float* __restrict__ sc,
                                                 u16* __restrict__ h){
  int row = blockIdx.x, t = threadIdx.x;
  float4 v = ((const float4*)(x + (size_t)row * DIM))[t];
  float ss = v.x*v.x + v.y*v.y + v.z*v.z + v.w*v.w;
  #pragma unroll
  for (int d = 32; d; d >>= 1) ss += __shfl_down(ss, d, 64);
  __shared__ float red[4];
  if ((t & 63) == 0) red[t >> 6] = ss;
  __syncthreads();
  float tot = red[0] + red[1] + red[2] + red[3];
  float rms = rsqrtf(tot * (1.0f / DIM) + 1e-6f);
  float4 s4 = ((const float4*)sc)[t];
  u16 ov[4];
  ov[0] = f2bf(v.x * rms * s4.x);
  ov[1] = f2bf(v.y * rms * s4.y);
  ov[2] = f2bf(v.z * rms * s4.z);
  ov[3] = f2bf(v.w * rms * s4.w);
  ((uint2*)(h + (size_t)row * DIM))[t] = *(uint2*)ov;
}

// ------- Weight transpose: fp32 K-major [1024][1024] -> bf16 N-major [n][k] -------
__global__ __launch_bounds__(256) void k_wtrans(const float* __restrict__ in0,
                                                const float* __restrict__ in1,
                                                const float* __restrict__ in2,
                                                u16* __restrict__ outT){
  __shared__ u16 tile[64][68];
  int t = threadIdx.x;
  int c0 = blockIdx.x * 64;   // n
  int r0 = blockIdx.y * 64;   // k
  int z = blockIdx.z;
  const float* in = (z == 0) ? in0 : ((z == 1) ? in1 : in2);
  u16* out = outT + (size_t)z * (1u << 20);
  #pragma unroll
  for (int i = 0; i < 4; i++){
    int idx = t + 256 * i;
    int r = idx >> 4, c4 = (idx & 15) * 4;
    float4 v = *(const float4*)&in[(size_t)(r0 + r) * 1024 + c0 + c4];
    u16 pk[4] = {f2bf(v.x), f2bf(v.y), f2bf(v.z), f2bf(v.w)};
    *(uint2*)&tile[r][c4] = *(uint2*)pk;
  }
  __syncthreads();
  #pragma unroll
  for (int i = 0; i < 2; i++){
    int c = t + 256 * i;
    int n = c >> 3, koff = (c & 7) * 8;
    alignas(16) u16 vals[8];
    #pragma unroll
    for (int j = 0; j < 8; j++) vals[j] = tile[koff + j][n];
    *(uint4*)&out[(size_t)(c0 + n) * 1024 + r0 + koff] = *(uint4*)vals;
  }
}

// ---------------- QKV GEMM (m97 structure): 128x128, BK=32 ----------------
// z=0 Q (scale 0.125, bf16), z=1 K (bf16), z=2 V^T (per-head transposed bf16).
__global__ __launch_bounds__(256) void k_gemm(const u16* __restrict__ A,
                                              const u16* __restrict__ B0,
                                              const u16* __restrict__ B1,
                                              const u16* __restrict__ B2,
                                              u16* __restrict__ C0,
                                              u16* __restrict__ C1,
                                              u16* __restrict__ C2,
                                              int dummy){
  __shared__ u16 Al[128][32];
  __shared__ u16 Bl[128][32];
  int t = threadIdx.x, lane = t & 63, w = t >> 6;
  int wm = w & 1, wn = w >> 1;
  int mrow = lane & 15, quad = lane >> 4;
  int m0 = blockIdx.x * 128, n0 = blockIdx.y * 128;
  int z = blockIdx.z;
  const u16* Bt = (z == 0) ? B0 : ((z == 1) ? B1 : B2);

  int r0s = (t * 16) >> 6, off0 = ((t * 16) & 63) >> 1;
  int r1s = r0s + 64;

  f32x4 acc[4][4];
  #pragma unroll
  for (int ms = 0; ms < 4; ms++)
    #pragma unroll
    for (int ns = 0; ns < 4; ns++) acc[ms][ns] = (f32x4){0.f, 0.f, 0.f, 0.f};

  for (int kt = 0; kt < 32; kt++){
    int K0 = kt * 32;
    __syncthreads();
    GLD_LDS(&A [(size_t)(m0 + r0s) * 1024 + K0 + off0], &Al[r0s][off0]);
    GLD_LDS(&A [(size_t)(m0 + r1s) * 1024 + K0 + off0], &Al[r1s][off0]);
    GLD_LDS(&Bt[(size_t)(n0 + r0s) * 1024 + K0 + off0], &Bl[r0s][off0]);
    GLD_LDS(&Bt[(size_t)(n0 + r1s) * 1024 + K0 + off0], &Bl[r1s][off0]);
    __syncthreads();
    bf16x8 af[4], bf[4];
    #pragma unroll
    for (int ms = 0; ms < 4; ms++)
      af[ms] = *(const bf16x8*)&Al[wm * 64 + ms * 16 + mrow][quad * 8];
    #pragma unroll
    for (int ns = 0; ns < 4; ns++)
      bf[ns] = *(const bf16x8*)&Bl[wn * 64 + ns * 16 + mrow][quad * 8];
    #pragma unroll
    for (int ms = 0; ms < 4; ms++)
      #pragma unroll
      for (int ns = 0; ns < 4; ns++)
        acc[ms][ns] = __builtin_amdgcn_mfma_f32_16x16x32_bf16(af[ms], bf[ns], acc[ms][ns], 0, 0, 0);
  }

  float qscale = (z == 0) ? 0.125f : 1.0f;
  bool  vmode  = (z == 2);
  u16* C = (z == 0) ? C0 : ((z == 1) ? C1 : C2);

  #pragma unroll
  for (int ms = 0; ms < 4; ms++){
    #pragma unroll
    for (int ns = 0; ns < 4; ns++){
      int col = n0 + wn * 64 + ns * 16 + mrow;
      int rbase = m0 + wm * 64 + ms * 16 + quad * 4;
      if (vmode){
        int b = rbase >> 11, sl = rbase & 2047;
        int hh = col >> 6, e = col & 63;
        uint2 pk = { pack2bf(acc[ms][ns][0], acc[ms][ns][1]),
                     pack2bf(acc[ms][ns][2], acc[ms][ns][3]) };
        *(uint2*)&C[(size_t)((b * NH + hh) * DH + e) * SEQ + sl] = pk;
      } else {
        #pragma unroll
        for (int r = 0; r < 4; r++)
          C[(size_t)(rbase + r) * 1024 + col] = f2bf(acc[ms][ns][r] * qscale);
      }
    }
  }
}

// ---------------- Out-projection GEMM: 128m x 64n, BK=32 (512 blocks) ----------------
__global__ __launch_bounds__(256) void k_gemm_o(const u16* __restrict__ A,
                                               const u16* __restrict__ Bt,
                                               float* __restrict__ C,
                                               const float* __restrict__ bias){
  __shared__ u16 Al[128][32];
  __shared__ u16 Bl[64][32];
  int t = threadIdx.x, lane = t & 63, w = t >> 6;
  int mrow = lane & 15, quad = lane >> 4;
  int m0 = blockIdx.x * 128, n0 = blockIdx.y * 64;
  int ra = t >> 2, oa = (t & 3) * 8;   // A: 512 chunks -> 2 calls; B: 256 -> 1 call

  f32x4 acc[2][4];
  #pragma unroll
  for (int ms = 0; ms < 2; ms++)
    #pragma unroll
    for (int ns = 0; ns < 4; ns++) acc[ms][ns] = (f32x4){0.f, 0.f, 0.f, 0.f};

  for (int kt = 0; kt < 32; kt++){
    int K0 = kt * 32;
    __syncthreads();
    GLD_LDS(&A [(size_t)(m0 + ra) * 1024 + K0 + oa],      &Al[ra][oa]);
    GLD_LDS(&A [(size_t)(m0 + ra + 64) * 1024 + K0 + oa], &Al[ra + 64][oa]);
    GLD_LDS(&Bt[(size_t)(n0 + ra) * 1024 + K0 + oa],      &Bl[ra][oa]);
    __syncthreads();
    bf16x8 af[2], bf[4];
    #pragma unroll
    for (int ms = 0; ms < 2; ms++)
      af[ms] = *(const bf16x8*)&Al[w * 32 + ms * 16 + mrow][quad * 8];
    #pragma unroll
    for (int ns = 0; ns < 4; ns++)
      bf[ns] = *(const bf16x8*)&Bl[ns * 16 + mrow][quad * 8];
    #pragma unroll
    for (int ms = 0; ms < 2; ms++)
      #pragma unroll
      for (int ns = 0; ns < 4; ns++)
        acc[ms][ns] = __builtin_amdgcn_mfma_f32_16x16x32_bf16(af[ms], bf[ns], acc[ms][ns], 0, 0, 0);
  }
  #pragma unroll
  for (int ms = 0; ms < 2; ms++){
    #pragma unroll
    for (int ns = 0; ns < 4; ns++){
      int col = n0 + ns * 16 + mrow;
      float bv = bias[col];
      int rbase = m0 + w * 32 + ms * 16 + quad * 4;
      #pragma unroll
      for (int r = 0; r < 4; r++)
        C[(size_t)(rbase + r) * 1024 + col] = acc[ms][ns][r] + bv;
    }
  }
}

// ---------------- Flash attention v3: kk-split waves, zero P round-trip ----------------
// Block: 64 q x full kk sweep; K-tile 128 kk; wave w owns kk [w*32, w*32+32).
// Q (scaled 0.125) in registers as B-operand. S^T tiles use pi-interleaved K rows
// (pi(m) = (m>>2)*8 + (m&3), tiles at +0/+4) so MFMA C-layout == PV B-layout:
// P stays in registers. No-max softmax via __expf (|s|<~30, safe in fp32).
// Per-wave partial O reduced across waves through LDS once at the end.
__global__ __launch_bounds__(256, 3) void k_attn(const u16* q,
                                                 const u16* __restrict__ k,
                                                 const u16* __restrict__ vt,
                                                 u16* nv){
  __shared__ __align__(16) char smem[128*72*2 + 64*136*2];   // 35.8 KB
  u16 (*Kl)[72]  = (u16(*)[72])smem;
  u16 (*Vl)[136] = (u16(*)[136])(smem + 128*72*2);

  int t = threadIdx.x, lane = t & 63, w = t >> 6;
  int mrow = lane & 15, quad = lane >> 4;
  int s0 = blockIdx.x * 64;
  int bh = blockIdx.y; int b = bh >> 4, hh = bh & 15;

  // Q fragments (B-operand), loaded once
  bf16x8 bq[4][2];
  #pragma unroll
  for (int qg = 0; qg < 4; qg++){
    const u16* qr = q + (size_t)((b * SEQ + s0 + qg * 16 + mrow) * NH + hh) * DH;
    bq[qg][0] = *(const bf16x8*)(qr + quad * 8);
    bq[qg][1] = *(const bf16x8*)(qr + 32 + quad * 8);
  }

  f32x4 o[4][4];
  #pragma unroll
  for (int eg = 0; eg < 4; eg++)
    #pragma unroll
    for (int qg = 0; qg < 4; qg++) o[eg][qg] = (f32x4){0.f, 0.f, 0.f, 0.f};
  float lacc[4] = {0.f, 0.f, 0.f, 0.f};

  int prow = (mrow >> 2) * 8 + (mrow & 3);   // pi(mrow)

  for (int kt = 0; kt < 16; kt++){
    int kk0 = kt * 128;
    __syncthreads();
    #pragma unroll
    for (int i = 0; i < 4; i++){
      int c = t + 256 * i; int r = c >> 3, off = (c & 7) * 8;
      *(uint4*)&Kl[r][off] =
        *(const uint4*)&k[(size_t)((b * SEQ + kk0 + r) * NH + hh) * DH + off];
    }
    #pragma unroll
    for (int i = 0; i < 4; i++){
      int c = t + 256 * i; int e = c >> 4, off = (c & 15) * 8;
      *(uint4*)&Vl[e][off] =
        *(const uint4*)&vt[(size_t)(bh * DH + e) * SEQ + kk0 + off];
    }
    __syncthreads();

    // QK: two pi-interleaved 16-row tiles (A and B) per wave
    bf16x8 ka[2][2];
    #pragma unroll
    for (int p = 0; p < 2; p++){
      int row = w * 32 + prow + p * 4;
      ka[p][0] = *(const bf16x8*)&Kl[row][quad * 8];
      ka[p][1] = *(const bf16x8*)&Kl[row][32 + quad * 8];
    }
    bf16x8 pb[4];
    #pragma unroll
    for (int qg = 0; qg < 4; qg++){
      f32x4 sA = (f32x4){0.f, 0.f, 0.f, 0.f};
      f32x4 sB = (f32x4){0.f, 0.f, 0.f, 0.f};
      sA = __builtin_amdgcn_mfma_f32_16x16x32_bf16(ka[0][0], bq[qg][0], sA, 0, 0, 0);
      sA = __builtin_amdgcn_mfma_f32_16x16x32_bf16(ka[0][1], bq[qg][1], sA, 0, 0, 0);
      sB = __builtin_amdgcn_mfma_f32_16x16x32_bf16(ka[1][0], bq[qg][0], sB, 0, 0, 0);
      sB = __builtin_amdgcn_mfma_f32_16x16x32_bf16(ka[1][1], bq[qg][1], sB, 0, 0, 0);
      float eA[4], eB[4], ps = 0.f;
      #pragma unroll
      for (int r = 0; r < 4; r++){
        eA[r] = __expf(sA[r]); eB[r] = __expf(sB[r]);
        ps += eA[r] + eB[r];
      }
      lacc[qg] += ps;
      u32 pw[4] = { pack2bf(eA[0], eA[1]), pack2bf(eA[2], eA[3]),
                    pack2bf(eB[0], eB[1]), pack2bf(eB[2], eB[3]) };
      __builtin_memcpy(&pb[qg], pw, 16);
    }

    // PV: K=32 over the wave's kk slice; P is register-resident B-operand
    #pragma unroll
    for (int eg = 0; eg < 4; eg++){
      bf16x8 va = *(const bf16x8*)&Vl[eg * 16 + mrow][w * 32 + quad * 8];
      #pragma unroll
      for (int qg = 0; qg < 4; qg++)
        o[eg][qg] = __builtin_amdgcn_mfma_f32_16x16x32_bf16(va, pb[qg], o[eg][qg], 0, 0, 0);
    }
  }

  // ---- end-of-block reductions ----
  __syncthreads();
  float* lbuf = (float*)Vl;          // 4 x 64 floats
  #pragma unroll
  for (int qg = 0; qg < 4; qg++){
    float v = lacc[qg];
    v += __shfl_xor(v, 16, 64);
    v += __shfl_xor(v, 32, 64);
    if (quad == 0) lbuf[w * 64 + qg * 16 + mrow] = v;
  }
  __syncthreads();
  float rl[4];
  #pragma unroll
  for (int qg = 0; qg < 4; qg++)
    rl[qg] = 1.0f / (lbuf[qg * 16 + mrow] + lbuf[64 + qg * 16 + mrow] +
                     lbuf[128 + qg * 16 + mrow] + lbuf[192 + qg * 16 + mrow]);

  float (*obuf)[68] = (float(*)[68])Kl;   // 64 q x 68 floats = 17.4 KB (fits in Kl)
  for (int ph = 0; ph < 3; ph++){
    if (w == ph){
      #pragma unroll
      for (int eg = 0; eg < 4; eg++)
        #pragma unroll
        for (int qg = 0; qg < 4; qg++){
          f32x4 v = o[eg][qg];
          if (ph > 0) v += *(f32x4*)&obuf[qg * 16 + mrow][eg * 16 + quad * 4];
          *(f32x4*)&obuf[qg * 16 + mrow][eg * 16 + quad * 4] = v;
        }
    }
    __syncthreads();
  }
  if (w == 3){
    #pragma unroll
    for (int eg = 0; eg < 4; eg++)
      #pragma unroll
      for (int qg = 0; qg < 4; qg++){
        f32x4 v = o[eg][qg] + *(f32x4*)&obuf[qg * 16 + mrow][eg * 16 + quad * 4];
        float s = rl[qg];
        u16* orow = nv + (size_t)((b * SEQ + s0 + qg * 16 + mrow) * NH + hh) * DH
                       + eg * 16 + quad * 4;
        uint2 pk = { pack2bf(v[0] * s, v[1] * s), pack2bf(v[2] * s, v[3] * s) };
        *(uint2*)orow = pk;
      }
  }
}

extern "C" void kernel_launch(void* const* d_in, const int* in_sizes, int n_in,
                              void* d_out, int out_size, void* d_ws, size_t ws_size,
                              hipStream_t stream){
  const float* x   = (const float*)d_in[0];
  const float* nsc = (const float*)d_in[1];
  const float* wq  = (const float*)d_in[2];
  const float* wk  = (const float*)d_in[3];
  const float* wv  = (const float*)d_in[4];
  const float* wo  = (const float*)d_in[5];
  const float* bo  = (const float*)d_in[6];
  char* ws = (char*)d_ws;
  const size_t MB = (size_t)1 << 20;

  // d_out (fp32, 16 MB): h bf16 [0,8M) + wqT/wkT/wvT [8,14M), dead after QKV GEMM;
  // final GEMM overwrites d_out in fp32.
  // ws (24 MB): qb | kb | vtb. attn writes in-place into qb; woT reuses kb after attn.
  u16* qb  = (u16*)(ws);
  u16* kb  = (u16*)(ws + 8  * MB);
  u16* vtb = (u16*)(ws + 16 * MB);
  u16* h   = (u16*)d_out;
  u16* wT  = (u16*)((char*)d_out + 8 * MB);
  u16* wqT = wT;
  u16* wkT = wT + (1u << 20);
  u16* wvT = wT + (2u << 20);
  u16* woT = kb;

  k_rmsnorm<<<NROW, 256, 0, stream>>>(x, nsc, h);
  k_wtrans<<<dim3(16, 16, 3), 256, 0, stream>>>(wq, wk, wv, wT);
  k_gemm<<<dim3(32, 8, 3), 256, 0, stream>>>(h, wqT, wkT, wvT, qb, kb, vtb, 0);
  k_attn<<<dim3(32, 32, 1), 256, 0, stream>>>(qb, kb, vtb, qb);
  k_wtrans<<<dim3(16, 16, 1), 256, 0, stream>>>(wo, wo, wo, woT);
  k_gemm_o<<<dim3(32, 16, 1), 256, 0, stream>>>(qb, woT, (float*)d_out, bo);
}